// Round 23
// baseline (451.474 us; speedup 1.0000x reference)
//
#include <hip/hip_runtime.h>
#include <hip/hip_cooperative_groups.h>

namespace cg = cooperative_groups;

#define NV 16384
#define EH 16256
#define EVV 16256
#define ED 16129
#define NE 48641
#define NT 32258
#define ND 32259
#define OUTERF 32258
#define TAILN 8192
#define FINT 1024

typedef unsigned int u32;
typedef unsigned short u16;

// ---------------- ws layout ----------------
static __host__ __device__ constexpr size_t al256(size_t x) { return (x + 255) & ~(size_t)255; }
static constexpr size_t OFF_ACC   = 0;                                  // acc[0..12)
static constexpr size_t OFF_R32   = 256;                                // u32[NV]
static constexpr size_t OFF_FVAL  = OFF_R32   + al256(NV * 4);          // f32[ND]
static constexpr size_t OFF_CTV   = OFF_FVAL  + al256(ND * 4);          // u16[NT]
static constexpr size_t OFF_CNTR  = OFF_CTV   + al256(NT * 2);          // u32[NV]
static constexpr size_t OFF_FRK   = OFF_CNTR  + al256(NV * 4);          // u32[ND]
static constexpr size_t OFF_FRV   = OFF_FRK   + al256(ND * 4);          // f32[ND]
static constexpr size_t OFF_DVAL  = OFF_FRV   + al256(ND * 4);          // f32[NE]
static constexpr size_t OFF_WLA   = OFF_DVAL  + al256(NE * 4);          // uint2[NE]
static constexpr size_t OFF_WLB   = OFF_WLA   + al256(NE * 8);          // uint2[NE]
static constexpr size_t OFF_RTS   = OFF_WLB   + al256(NE * 8);          // u32[NE]
static constexpr size_t OFF_RTS2  = OFF_RTS   + al256(NE * 4);          // u32[NE]
static constexpr size_t OFF_MTG   = OFF_RTS2  + al256(NE * 4);          // u32[ND+1]
static constexpr size_t OFF_MTG2  = OFF_MTG   + al256((ND + 1) * 4);    // u32[ND+1]
static constexpr size_t OFF_PARG  = OFF_MTG2  + al256((ND + 1) * 4);    // u16[ND+1]

__device__ __forceinline__ u32 fmap(float x) {
  u32 u = __float_as_uint(x);
  return (u & 0x80000000u) ? ~u : (u | 0x80000000u);
}
__device__ __forceinline__ float funmap(u32 m) {
  u32 u = (m & 0x80000000u) ? (m & 0x7FFFFFFFu) : ~m;
  return __uint_as_float(u);
}

__device__ __forceinline__ int findh(volatile u16* par, int x) {
  while (true) {
    int p = par[x];
    if (p == x) return x;
    int gp = par[p];
    if (gp == p) return p;
    par[x] = (u16)gp;
    x = gp;
  }
}

// edge eid -> primal endpoints
__device__ __forceinline__ void decode_pe(u32 e, int& eu, int& ev) {
  if (e < EH) { int i = (int)(e / 127u), j = (int)(e - (u32)i * 127u); eu = (i << 7) + j; ev = eu + 1; }
  else if (e < EH + EVV) { int k = (int)(e - EH); eu = k; ev = k + 128; }
  else { int k = (int)(e - EH - EVV); int i = k / 127, j = k - i * 127; eu = (i << 7) + j; ev = eu + 129; }
}
// edge eid -> dual faces
__device__ __forceinline__ void decode_df(u32 e, int& fa, int& fb) {
  if (e < EH) { int i = (int)(e / 127u), j = (int)(e - (u32)i * 127u);
    fa = (i < 127) ? (ED + i * 127 + j) : OUTERF;
    fb = (i >= 1) ? ((i - 1) * 127 + j) : OUTERF; }
  else if (e < EH + EVV) { int k = (int)(e - EH); int i = k >> 7, j = k & 127;
    fa = (j < 127) ? (i * 127 + j) : OUTERF;
    fb = (j >= 1) ? (ED + i * 127 + (j - 1)) : OUTERF; }
  else { int k = (int)(e - EH - EVV); int i = k / 127, j = k - i * 127;
    fa = i * 127 + j; fb = ED + i * 127 + j; }
}

// ---------------- K0: init ----------------
// acc: F[0]=sum dv(all), F[1]=sum beta, U[2]=max beta(fmap), F[3]=sum fval(faces),
//      F[4]=wD partial, U[5]=lmax partial (fmap), U[6..10)=survivor counts r0..r3
__global__ void k_init(float* accF, u32* r32, u32* mtabG, u32* mtabG2, u32* parG32) {
  int i = blockIdx.x * 256 + threadIdx.x;
  if (i < 12) accF[i] = 0.f;
  if (i < NV) r32[i] = 0u;
  if (i < (ND + 1) / 2) parG32[i] = ((2u * (u32)i + 1u) << 16) | (2u * (u32)i);
  if (i < ND + 1) { mtabG[i] = 0xFFFFFFFFu; mtabG2[i] = 0xFFFFFFFFu; }
}

// ---------------- K1: vertex ranks (ascending beta, id tiebreak) ----------------
__global__ void k_rankv(const float* __restrict__ beta, u32* r32) {
  int v = blockIdx.x * 256 + threadIdx.x;
  int c = blockIdx.y;
  float bv = beta[v];
  int u0 = c << 10;
  int cnt = 0;
#pragma unroll 8
  for (int u = u0; u < u0 + 1024; ++u) {
    float bu = beta[u];
    cnt += (bu < bv || (bu == bv && u < v)) ? 1 : 0;
  }
  if (cnt) atomicAdd(&r32[v], (u32)cnt);
}

// ---------------- K_COOP: build..facerank..edges + offloaded rounds 0-3 ----------------
// 191 blocks x 256 threads (natural grid of every phase); grid.sync() replaces
// kernel boundaries; memsets replaced by claimed-slot resets on independent tables.
__global__ __launch_bounds__(256) void k_coop(
    const float* __restrict__ beta, const u32* __restrict__ r32,
    float* accF, u32* accU,
    float* fval, u16* ctv, u32* cntR, u32* frk, float* frv,
    float* dvals, uint2* wlA, uint2* wlB, u32* rts, u32* rts2,
    u32* mtabG, u32* mtabG2, u16* parG) {
  cg::grid_group grid = cg::this_grid();
  __shared__ float ls[4], lm[4];
  __shared__ u32 wsum[4];
  int tid = threadIdx.x, lane = tid & 63, wid = tid >> 6;
  int bid = blockIdx.x;
  int gtid = bid * 256 + tid;
  // ---- P0: face values + crit vertex + reductions (k_build role split) ----
  if (bid < 64) {
    int v = (bid << 8) + tid;
    float b = beta[v];
    float s = b, m = b;
    for (int off = 32; off >= 1; off >>= 1) {
      s += __shfl_down(s, off);
      m = fmaxf(m, __shfl_down(m, off));
    }
    if (lane == 0) { ls[wid] = s; lm[wid] = m; }
    __syncthreads();
    if (tid == 0) {
      s = ls[0] + ls[1] + ls[2] + ls[3];
      m = fmaxf(fmaxf(lm[0], lm[1]), fmaxf(lm[2], lm[3]));
      atomicAdd(&accF[1], s);
      atomicMax(&accU[2], fmap(m));
    }
  } else {
    int t = ((bid - 64) << 8) + tid;
    float c = 0.f;
    if (t < NT) {
      int i, j, v0, v1, v2;
      if (t < ED) { i = t / 127; j = t - i * 127; v0 = (i << 7) + j; v1 = v0 + 128; v2 = v0 + 129; } // L
      else { int u = t - ED; i = u / 127; j = u - i * 127; v0 = (i << 7) + j; v1 = v0 + 1; v2 = v0 + 129; } // U
      u32 r0 = r32[v0], r1 = r32[v1], r2 = r32[v2];
      int crit = v0; u32 rm = r0;
      if (r1 < rm) { rm = r1; crit = v1; }
      if (r2 < rm) { rm = r2; crit = v2; }
      float fv = -beta[crit];
      fval[t] = fv;
      ctv[t] = (u16)crit;
      c = fv;
      if (t == 0) fval[OUTERF] = __builtin_inff();
    }
    for (int off = 32; off >= 1; off >>= 1) c += __shfl_down(c, off);
    if (lane == 0) ls[wid] = c;
    __syncthreads();
    if (tid == 0) atomicAdd(&accF[3], ls[0] + ls[1] + ls[2] + ls[3]);
  }
  grid.sync();
  // ---- P1: per-vertex crit-face counts into rank buckets ----
  if (gtid < NV) {
    int v = gtid;
    int i = v >> 7, j = v & 127;
    int cnt = 0;
    if (i < 127 && j < 127) cnt += (ctv[i * 127 + j] == v);
    if (i >= 1 && j < 127)  cnt += (ctv[(i - 1) * 127 + j] == v);
    if (i >= 1 && j >= 1)   cnt += (ctv[(i - 1) * 127 + (j - 1)] == v);
    if (i < 127 && j < 127) cnt += (ctv[ED + i * 127 + j] == v);
    if (i < 127 && j >= 1)  cnt += (ctv[ED + i * 127 + (j - 1)] == v);
    if (i >= 1 && j >= 1)   cnt += (ctv[ED + (i - 1) * 127 + (j - 1)] == v);
    cntR[r32[v]] = (u32)cnt;
  }
  grid.sync();
  // ---- P2: exclusive scan over NV buckets (block 0, two-pass, +1 outer face) ----
  if (bid == 0) {
    int b0 = tid << 6;
    u32 s = 0;
    for (int k = 0; k < 64; ++k) s += cntR[b0 + k];
    u32 incl = s;
    for (int off = 1; off < 64; off <<= 1) {
      u32 o = __shfl_up(incl, off);
      if (lane >= off) incl += o;
    }
    if (lane == 63) wsum[wid] = incl;
    __syncthreads();
    u32 wbase = 0;
    for (int w = 0; w < wid; ++w) wbase += wsum[w];
    u32 running = wbase + incl - s + 1;
    for (int k = 0; k < 64; ++k) {
      u32 c = cntR[b0 + k];
      cntR[b0 + k] = running;
      running += c;
    }
  }
  grid.sync();
  // ---- P3: face ranks + rank->value table ----
  if (gtid == 0) { frk[OUTERF] = 0u; frv[0] = __builtin_inff(); }
  if (gtid < NT) {
    int g = gtid;
    int v = ctv[g];
    int i = v >> 7, j = v & 127;
    int local = 0, f;
    if (i < 127 && j < 127) { f = i * 127 + j;             local += (f < g && ctv[f] == v); }
    if (i >= 1 && j < 127)  { f = (i - 1) * 127 + j;       local += (f < g && ctv[f] == v); }
    if (i >= 1 && j >= 1)   { f = (i - 1) * 127 + (j - 1); local += (f < g && ctv[f] == v); }
    if (i < 127 && j < 127) { f = ED + i * 127 + j;        local += (f < g && ctv[f] == v); }
    if (i < 127 && j >= 1)  { f = ED + i * 127 + (j - 1);  local += (f < g && ctv[f] == v); }
    if (i >= 1 && j >= 1)   { f = ED + (i - 1) * 127 + (j - 1); local += (f < g && ctv[f] == v); }
    u32 rk = cntR[r32[v]] + (u32)local;
    frk[g] = rk;
    frv[rk] = fval[g];
  }
  grid.sync();
  // ---- P4: edge values + records + total sum + round-0 claims (mtabG, full size) ----
  {
    int e = gtid;
    float dv = 0.f;
    if (e < NE) {
      int eu, ev; decode_pe((u32)e, eu, ev);
      int fa, fb; decode_df((u32)e, fa, fb);
      u32 ru = r32[eu], rv = r32[ev];
      u32 rr = min(ru, rv);
      int cv = (ru <= rv) ? eu : ev;
      dv = -beta[cv];
      dvals[e] = dv;
      u32 ra = frk[fa], rb = frk[fb];
      u32 key = (rr << 17) | (u32)e;
      wlA[e] = make_uint2(ra | (rb << 16), key);
      atomicMin(&mtabG[ra], key);
      atomicMin(&mtabG[rb], key);
    }
    float ds = dv;
    for (int off = 32; off >= 1; off >>= 1) ds += __shfl_down(ds, off);
    if (lane == 0 && ds != 0.f) atomicAdd(&accF[0], ds);
  }
  grid.sync();
  // ---- P5: round-0 win-younger commits -> wlB, accU[6] ----
  {
    float wDl = 0.f, lmx = 0.f;
    bool surv = false;
    uint2 rec = make_uint2(0u, 0u);
    if (gtid < NE) {
      rec = wlA[gtid];
      u32 a = rec.x & 0xFFFFu, b = rec.x >> 16;
      u32 y = max(a, b), o = min(a, b);
      if (mtabG[y] == rec.y) {
        parG[y] = (u16)o;
        float dv = dvals[rec.y & 0x1FFFFu];
        wDl = dv;
        lmx = frv[y] - dv;
      } else {
        surv = true;
      }
    }
    unsigned long long mk = __ballot(surv);
    int base = 0;
    if (lane == 0) {
      int c = __popcll(mk);
      if (c) base = (int)atomicAdd(&accU[6], (u32)c);
    }
    base = __shfl(base, 0);
    if (surv) wlB[base + __popcll(mk & ((1ull << lane) - 1ull))] = rec;
    for (int off = 32; off >= 1; off >>= 1) {
      wDl += __shfl_down(wDl, off);
      lmx = fmaxf(lmx, __shfl_down(lmx, off));
    }
    if (lane == 0) { ls[wid] = wDl; lm[wid] = lmx; }
    __syncthreads();
    if (tid == 0) {
      atomicAdd(&accF[4], ls[0] + ls[1] + ls[2] + ls[3]);
      atomicMax(&accU[5], fmap(fmaxf(fmaxf(lm[0], lm[1]), fmaxf(lm[2], lm[3]))));
    }
  }
  grid.sync();
  // ---- rounds 1..3: claim/win with grid.sync; table recycling via claimed-slot resets ----
  // round r claims table (r odd -> mtabG2, r even -> mtabG); rts/rts2 alternate.
  for (int r = 1; r <= 3; ++r) {
    u32* mt = (r & 1) ? mtabG2 : mtabG;
    u32* rt = (r & 1) ? rts : rts2;
    const uint2* inl = (r & 1) ? wlB : wlA;
    uint2* outl = (r & 1) ? wlA : wlB;
    int ci = 5 + r, co = 6 + r;
    // claim phase (+ piggybacked reset of the OTHER table's previous claims)
    if (r == 2) {                                  // reset round-0 claims (mtabG2? no: reset mtabG2 needs r1 pairs)
      int n1 = (int)accU[6];
      if (gtid < n1) {                             // reset round-1 claimed slots in mtabG2
        u32 pr = rts[gtid];
        if (pr != 0xFFFFFFFFu) { mtabG2[pr & 0xFFFFu] = 0xFFFFFFFFu; mtabG2[pr >> 16] = 0xFFFFFFFFu; }
      }
    }
    if (r == 1) {                                  // reset round-0 claims in mtabG (via wlA records)
      if (gtid < NE) {
        u32 x = wlA[gtid].x;
        mtabG[x & 0xFFFFu] = 0xFFFFFFFFu;
        mtabG[x >> 16] = 0xFFFFFFFFu;
      }
    }
    {
      int n1 = (int)accU[ci];
      if (gtid < n1) {
        uint2 rec = inl[gtid];
        int ra = findh((volatile u16*)parG, (int)(rec.x & 0xFFFFu));
        int rb = findh((volatile u16*)parG, (int)(rec.x >> 16));
        if (ra == rb) {
          rt[gtid] = 0xFFFFFFFFu;
        } else {
          rt[gtid] = (u32)ra | ((u32)rb << 16);
          atomicMin(&mt[ra], rec.y);
          atomicMin(&mt[rb], rec.y);
        }
      }
    }
    grid.sync();
    // win phase
    {
      int n1 = (int)accU[ci];
      bool active = gtid < n1;
      float wDl = 0.f, lmx = 0.f;
      bool surv = false;
      u32 pr = 0xFFFFFFFFu, key = 0;
      if (active) {
        key = inl[gtid].y;
        pr = rt[gtid];
      }
      if (active && pr != 0xFFFFFFFFu) {
        u32 a = pr & 0xFFFFu, b = pr >> 16;
        u32 y = max(a, b), o = min(a, b);
        if (mt[y] == key) {
          parG[y] = (u16)o;
          float dv = dvals[key & 0x1FFFFu];
          wDl = dv;
          lmx = frv[y] - dv;
        } else {
          surv = true;
        }
      }
      unsigned long long mk = __ballot(surv);
      int base = 0;
      if (lane == 0) {
        int c = __popcll(mk);
        if (c) base = (int)atomicAdd(&accU[co], (u32)c);
      }
      base = __shfl(base, 0);
      if (surv) outl[base + __popcll(mk & ((1ull << lane) - 1ull))] = make_uint2(pr, key);
      for (int off = 32; off >= 1; off >>= 1) {
        wDl += __shfl_down(wDl, off);
        lmx = fmaxf(lmx, __shfl_down(lmx, off));
      }
      if (lane == 0) { ls[wid] = wDl; lm[wid] = lmx; }
      __syncthreads();
      if (tid == 0) {
        atomicAdd(&accF[4], ls[0] + ls[1] + ls[2] + ls[3]);
        atomicMax(&accU[5], fmap(fmaxf(fmaxf(lm[0], lm[1]), fmaxf(lm[2], lm[3]))));
      }
    }
    grid.sync();
  }
}

// ---------------- K5: unified dual Kruskal from round 4 (identical to round 22) ----------------
__global__ __launch_bounds__(1024) void k_dual(
    uint2* __restrict__ wlA, uint2* __restrict__ wlB, u32* __restrict__ rts,
    const u32* __restrict__ parG32, const float* __restrict__ dvals,
    const float* __restrict__ frv,
    const float* __restrict__ accF, const u32* __restrict__ accU, float* out) {
  __shared__ u16 par[ND + 1];      // 64520 B
  __shared__ u32 pool[24576];      // 98304 B
  __shared__ int nCur, nNxt;
  __shared__ int nTail[2];
  __shared__ float redS[16], redM[16];
  int tid = threadIdx.x, lane = tid & 63;
  {
    u32* p32 = (u32*)par;
    for (int v = tid; v < (ND + 1) / 2; v += 1024) p32[v] = parG32[v];
  }
  for (int h = tid; h < 16384; h += 1024) pool[h] = 0xFFFFFFFFu;
  if (tid == 0) { nNxt = 0; nTail[0] = 0; nTail[1] = 0; nCur = (int)accU[9]; }
  float wD = 0.f, lmax = 0.f;
  __syncthreads();
  uint2* cur = wlA;
  uint2* nxt = wlB;
  int n = nCur;
  for (int round = 0; round < 50000 && n > TAILN; ++round) {
    for (int i0 = 0; i0 < n; i0 += 1024) {
      int i = i0 + tid;
      if (i < n) {
        uint2 rec = cur[i];
        int ra = findh((volatile u16*)par, (int)(rec.x & 0xFFFFu));
        int rb = findh((volatile u16*)par, (int)(rec.x >> 16));
        if (ra == rb) {
          rts[i] = 0xFFFFFFFFu;
        } else {
          rts[i] = (u32)ra | ((u32)rb << 16);
          atomicMin(&pool[(u32)ra & 16383u], rec.y);
          atomicMin(&pool[(u32)rb & 16383u], rec.y);
        }
      }
    }
    __syncthreads();
    for (int i0 = 0; i0 < n; i0 += 1024) {
      int i = i0 + tid;
      bool active = i < n;
      u32 pr = 0xFFFFFFFFu, key = 0;
      if (active) {
        key = cur[i].y;
        pr = rts[i];
      }
      bool pend = active && (pr != 0xFFFFFFFFu);
      u32 y = 0, o = 0;
      bool win = false;
      if (pend) {
        u32 a = pr & 0xFFFFu, b = pr >> 16;
        y = max(a, b); o = min(a, b);
        win = (pool[y & 16383u] == key);
      }
      if (win) {
        par[y] = (u16)o;
        float dv = dvals[key & 0x1FFFFu];
        wD += dv;
        lmax = fmaxf(lmax, frv[y] - dv);
      }
      bool req = pend && !win;
      unsigned long long mk = __ballot(req);
      int base = 0;
      if (lane == 0) {
        int c = __popcll(mk);
        if (c) base = atomicAdd(&nNxt, c);
      }
      base = __shfl(base, 0);
      if (req) {
        int pos = base + __popcll(mk & ((1ull << lane) - 1ull));
        nxt[pos] = make_uint2(pr, key);
      }
    }
    __syncthreads();
    if (n <= 6144) {
      for (int i0 = 0; i0 < n; i0 += 1024) {
        int i = i0 + tid;
        if (i < n) {
          u32 pr = rts[i];
          if (pr != 0xFFFFFFFFu) {
            pool[(pr & 0xFFFFu) & 16383u] = 0xFFFFFFFFu;
            pool[(pr >> 16) & 16383u] = 0xFFFFFFFFu;
          }
        }
      }
    } else {
      for (int h = tid; h < 16384; h += 1024) pool[h] = 0xFFFFFFFFu;
    }
    for (int v = tid; v < ND; v += 1024) {
      int p = par[v]; int pp = par[p];
      if (p != pp) par[v] = (u16)pp;
    }
    if (tid == 0) { nCur = nNxt; nNxt = 0; }
    __syncthreads();
    n = nCur;
    uint2* s = cur; cur = nxt; nxt = s;
  }
  if (n > 0) {
    uint2* wlL = (uint2*)(pool + 8192);
    for (int i = tid; i < n; i += 1024) wlL[i] = cur[i];
    __syncthreads();
    int nL = n;
    int cb = 0;
    u32 oldp[8];
#pragma unroll
    for (int k = 0; k < 8; ++k) oldp[k] = 0xFFFFFFFFu;
    for (int sr = 0; sr < 100000; ++sr) {
      if (nL <= FINT) break;
      u32* mtC = pool + (cb << 12);
      u32* mtO = pool + ((cb ^ 1) << 12);
      u32 prc[8], keyr[8];
#pragma unroll
      for (int k = 0; k < 8; ++k) {
        if (oldp[k] != 0xFFFFFFFFu) {
          mtO[(oldp[k] & 0xFFFFu) & 4095u] = 0xFFFFFFFFu;
          mtO[(oldp[k] >> 16) & 4095u] = 0xFFFFFFFFu;
        }
        prc[k] = 0xFFFFFFFFu; keyr[k] = 0u;
        int i = tid + (k << 10);
        if (i < nL) {
          uint2 rec = wlL[i];
          int ra = findh((volatile u16*)par, (int)(rec.x & 0xFFFFu));
          int rb = findh((volatile u16*)par, (int)(rec.x >> 16));
          if (ra != rb) {
            u32 pr = (u32)ra | ((u32)rb << 16);
            prc[k] = pr; keyr[k] = rec.y;
            atomicMin(&mtC[(u32)ra & 4095u], rec.y);
            atomicMin(&mtC[(u32)rb & 4095u], rec.y);
          }
        }
      }
      if (tid == 0) nTail[cb] = 0;
      __syncthreads();
#pragma unroll
      for (int k = 0; k < 8; ++k) {
        bool surv = false;
        if (prc[k] != 0xFFFFFFFFu) {
          u32 a = prc[k] & 0xFFFFu, b = prc[k] >> 16;
          u32 y = max(a, b), o = min(a, b);
          if (mtC[y & 4095u] == keyr[k]) {
            par[y] = (u16)o;
            float dv = dvals[keyr[k] & 0x1FFFFu];
            wD += dv;
            lmax = fmaxf(lmax, frv[y] - dv);
          } else {
            surv = true;
          }
        }
        unsigned long long mk = __ballot(surv);
        int base = 0;
        if (lane == 0) {
          int c = __popcll(mk);
          if (c) base = atomicAdd(&nTail[cb], c);
        }
        base = __shfl(base, 0);
        if (surv) {
          int pos = base + __popcll(mk & ((1ull << lane) - 1ull));
          wlL[pos] = make_uint2(prc[k], keyr[k]);
        }
        oldp[k] = prc[k];
      }
      __syncthreads();
      nL = nTail[cb];
      cb ^= 1;
    }
    for (int h = tid; h < 8192; h += 1024) pool[h] = 0xFFFFFFFFu;
    __syncthreads();
    if (nL > 0 && tid < 64) {
      int m = nL;
      int mm = m;
      int guard = 0;
      while (mm > 0 && guard++ < 100000) {
        u32 prc[16];
        int resolved = 0;
#pragma unroll
        for (int k = 0; k < 16; ++k) {
          prc[k] = 0xFFFFFFFFu;
          int i = (k << 6) + lane;
          if (i < m) {
            uint2 rec = wlL[i];
            if (rec.x != 0xFFFFFFFFu) {
              int ra = findh((volatile u16*)par, (int)(rec.x & 0xFFFFu));
              int rb = findh((volatile u16*)par, (int)(rec.x >> 16));
              if (ra == rb) {
                wlL[i].x = 0xFFFFFFFFu;
                resolved++;
              } else {
                u32 pr = (u32)ra | ((u32)rb << 16);
                prc[k] = pr;
                wlL[i].x = pr;
                atomicMin(&pool[(u32)ra & 4095u], rec.y);
                atomicMin(&pool[(u32)rb & 4095u], rec.y);
              }
            }
          }
        }
        asm volatile("s_waitcnt lgkmcnt(0)" ::: "memory");
#pragma unroll
        for (int k = 0; k < 16; ++k) {
          if (prc[k] != 0xFFFFFFFFu) {
            int i = (k << 6) + lane;
            u32 key = wlL[i].y;
            u32 a = prc[k] & 0xFFFFu, b = prc[k] >> 16;
            u32 y = max(a, b), o = min(a, b);
            if (pool[y & 4095u] == key) {
              par[y] = (u16)o;
              float dv = dvals[key & 0x1FFFFu];
              wD += dv;
              lmax = fmaxf(lmax, frv[y] - dv);
              wlL[i].x = 0xFFFFFFFFu;
              resolved++;
            }
          }
        }
        asm volatile("s_waitcnt lgkmcnt(0)" ::: "memory");
#pragma unroll
        for (int k = 0; k < 16; ++k) {
          if (prc[k] != 0xFFFFFFFFu) {
            pool[(prc[k] & 0xFFFFu) & 4095u] = 0xFFFFFFFFu;
            pool[(prc[k] >> 16) & 4095u] = 0xFFFFFFFFu;
          }
        }
        asm volatile("s_waitcnt lgkmcnt(0)" ::: "memory");
        for (int off = 32; off >= 1; off >>= 1) resolved += __shfl_down(resolved, off);
        resolved = __shfl(resolved, 0);
        mm -= resolved;
      }
    }
  }
  __syncthreads();
  for (int off = 32; off >= 1; off >>= 1) {
    wD += __shfl_down(wD, off);
    lmax = fmaxf(lmax, __shfl_down(lmax, off));
  }
  if (lane == 0) { redS[tid >> 6] = wD; redM[tid >> 6] = lmax; }
  __syncthreads();
  if (tid == 0) {
    float s = 0.f, m = 0.f;
    for (int w = 0; w < 16; ++w) { s += redS[w]; m = fmaxf(m, redM[w]); }
    s += accF[4];
    m = fmaxf(m, funmap(accU[5]));
    float wmst = accF[0] - s;
    float loss0 = wmst + accF[1] - funmap(accU[2]);
    float sum1 = accF[3] - s;
    out[0] = loss0 + sum1 - m;
  }
}

extern "C" void kernel_launch(void* const* d_in, const int* in_sizes, int n_in,
                              void* d_out, int out_size, void* d_ws, size_t ws_size,
                              hipStream_t stream) {
  const float* beta = (const float*)d_in[0];
  float* out = (float*)d_out;
  char* ws = (char*)d_ws;
  float* accF = (float*)(ws + OFF_ACC);
  u32*   accU = (u32*)(ws + OFF_ACC);
  u32* r32 = (u32*)(ws + OFF_R32);
  float* fval = (float*)(ws + OFF_FVAL);
  u16* ctv = (u16*)(ws + OFF_CTV);
  u32* cntR = (u32*)(ws + OFF_CNTR);
  u32* frk = (u32*)(ws + OFF_FRK);
  float* frv = (float*)(ws + OFF_FRV);
  float* dvals = (float*)(ws + OFF_DVAL);
  uint2* wlA = (uint2*)(ws + OFF_WLA);
  uint2* wlB = (uint2*)(ws + OFF_WLB);
  u32* rts = (u32*)(ws + OFF_RTS);
  u32* rts2 = (u32*)(ws + OFF_RTS2);
  u32* mtabG = (u32*)(ws + OFF_MTG);
  u32* mtabG2 = (u32*)(ws + OFF_MTG2);
  u16* parG = (u16*)(ws + OFF_PARG);
  u32* parG32 = (u32*)(ws + OFF_PARG);

  hipLaunchKernelGGL(k_init, dim3(127), dim3(256), 0, stream, accF, r32, mtabG, mtabG2, parG32);
  hipLaunchKernelGGL(k_rankv, dim3(64, 16), dim3(256), 0, stream, beta, r32);
  void* kargs[] = { (void*)&beta, (void*)&r32, (void*)&accF, (void*)&accU,
                    (void*)&fval, (void*)&ctv, (void*)&cntR, (void*)&frk, (void*)&frv,
                    (void*)&dvals, (void*)&wlA, (void*)&wlB, (void*)&rts, (void*)&rts2,
                    (void*)&mtabG, (void*)&mtabG2, (void*)&parG };
  hipLaunchCooperativeKernel((const void*)k_coop, dim3(191), dim3(256), kargs, 0, stream);
  hipLaunchKernelGGL(k_dual, dim3(1), dim3(1024), 0, stream, wlA, wlB, rts, parG32, dvals, frv, accF, accU, out);
}

// Round 24
// 250.799 us; speedup vs baseline: 1.8001x; 1.8001x over previous
//
#include <hip/hip_runtime.h>

#define NV 16384
#define EH 16256
#define EVV 16256
#define ED 16129
#define NE 48641
#define NT 32258
#define ND 32259
#define OUTERF 32258
#define TAILN 8192
#define FINT 1024

typedef unsigned int u32;
typedef unsigned short u16;

// ---------------- ws layout ----------------
static __host__ __device__ constexpr size_t al256(size_t x) { return (x + 255) & ~(size_t)255; }
static constexpr size_t OFF_ACC   = 0;                                  // acc[0..12)
static constexpr size_t OFF_R32   = 256;                                // u32[NV]
static constexpr size_t OFF_FVAL  = OFF_R32   + al256(NV * 4);          // f32[ND]
static constexpr size_t OFF_CTV   = OFF_FVAL  + al256(ND * 4);          // u16[NT]
static constexpr size_t OFF_CNTR  = OFF_CTV   + al256(NT * 2);          // u32[NV]
static constexpr size_t OFF_FRK   = OFF_CNTR  + al256(NV * 4);          // u32[ND]
static constexpr size_t OFF_FRV   = OFF_FRK   + al256(ND * 4);          // f32[ND]
static constexpr size_t OFF_DVAL  = OFF_FRV   + al256(ND * 4);          // f32[NE]
static constexpr size_t OFF_WLA   = OFF_DVAL  + al256(NE * 4);          // uint2[NE]
static constexpr size_t OFF_WLB   = OFF_WLA   + al256(NE * 8);          // uint2[NE]
static constexpr size_t OFF_RTS   = OFF_WLB   + al256(NE * 8);          // u32[NE]
static constexpr size_t OFF_MTG   = OFF_RTS   + al256(NE * 4);          // u32[ND+1]
static constexpr size_t OFF_MTG2  = OFF_MTG   + al256((ND + 1) * 4);    // u32[ND+1]
static constexpr size_t OFF_MTG3  = OFF_MTG2  + al256((ND + 1) * 4);    // u32[ND+1]
static constexpr size_t OFF_MTG4  = OFF_MTG3  + al256((ND + 1) * 4);    // u32[ND+1]
static constexpr size_t OFF_PARG  = OFF_MTG4  + al256((ND + 1) * 4);    // u16[ND+1]

__device__ __forceinline__ u32 fmap(float x) {
  u32 u = __float_as_uint(x);
  return (u & 0x80000000u) ? ~u : (u | 0x80000000u);
}
__device__ __forceinline__ float funmap(u32 m) {
  u32 u = (m & 0x80000000u) ? (m & 0x7FFFFFFFu) : ~m;
  return __uint_as_float(u);
}

__device__ __forceinline__ int findh(volatile u16* par, int x) {
  while (true) {
    int p = par[x];
    if (p == x) return x;
    int gp = par[p];
    if (gp == p) return p;
    par[x] = (u16)gp;
    x = gp;
  }
}

// edge eid -> primal endpoints
__device__ __forceinline__ void decode_pe(u32 e, int& eu, int& ev) {
  if (e < EH) { int i = (int)(e / 127u), j = (int)(e - (u32)i * 127u); eu = (i << 7) + j; ev = eu + 1; }
  else if (e < EH + EVV) { int k = (int)(e - EH); eu = k; ev = k + 128; }
  else { int k = (int)(e - EH - EVV); int i = k / 127, j = k - i * 127; eu = (i << 7) + j; ev = eu + 129; }
}
// edge eid -> dual faces
__device__ __forceinline__ void decode_df(u32 e, int& fa, int& fb) {
  if (e < EH) { int i = (int)(e / 127u), j = (int)(e - (u32)i * 127u);
    fa = (i < 127) ? (ED + i * 127 + j) : OUTERF;
    fb = (i >= 1) ? ((i - 1) * 127 + j) : OUTERF; }
  else if (e < EH + EVV) { int k = (int)(e - EH); int i = k >> 7, j = k & 127;
    fa = (j < 127) ? (i * 127 + j) : OUTERF;
    fb = (j >= 1) ? (ED + i * 127 + (j - 1)) : OUTERF; }
  else { int k = (int)(e - EH - EVV); int i = k / 127, j = k - i * 127;
    fa = i * 127 + j; fb = ED + i * 127 + j; }
}

// ---------------- K0: init ----------------
// acc: F[0]=sum dv(all), F[1]=sum beta, U[2]=max beta(fmap), F[3]=sum fval(faces),
//      F[4]=wD partial, U[5]=lmax partial (fmap), U[6..10)=survivor counts r0..r3
__global__ void k_init(float* accF, u32* r32, u32* mtabG, u32* mtabG2,
                       u32* mtabG3, u32* mtabG4, u32* parG32) {
  int i = blockIdx.x * 256 + threadIdx.x;
  if (i < 12) accF[i] = 0.f;
  if (i < NV) r32[i] = 0u;
  if (i < (ND + 1) / 2) parG32[i] = ((2u * (u32)i + 1u) << 16) | (2u * (u32)i);
  if (i < ND + 1) {
    mtabG[i] = 0xFFFFFFFFu; mtabG2[i] = 0xFFFFFFFFu;
    mtabG3[i] = 0xFFFFFFFFu; mtabG4[i] = 0xFFFFFFFFu;
  }
}

// ---------------- K1: vertex ranks (ascending beta, id tiebreak) ----------------
__global__ void k_rankv(const float* __restrict__ beta, u32* r32) {
  int v = blockIdx.x * 256 + threadIdx.x;
  int c = blockIdx.y;
  float bv = beta[v];
  int u0 = c << 10;
  int cnt = 0;
#pragma unroll 8
  for (int u = u0; u < u0 + 1024; ++u) {
    float bu = beta[u];
    cnt += (bu < bv || (bu == bv && u < v)) ? 1 : 0;
  }
  if (cnt) atomicAdd(&r32[v], (u32)cnt);
}

// ---------------- K2: face values + crit vertex + reductions ----------------
__global__ void k_build(const float* __restrict__ beta, const u32* __restrict__ r32,
                        float* fval, u16* ctv, float* accF, u32* accU) {
  __shared__ float ls[4], lm[4];
  int bid = blockIdx.x, tid = threadIdx.x;
  if (bid < 64) {
    int v = (bid << 8) + tid;
    float b = beta[v];
    float s = b, m = b;
    for (int off = 32; off >= 1; off >>= 1) {
      s += __shfl_down(s, off);
      m = fmaxf(m, __shfl_down(m, off));
    }
    int wid = tid >> 6;
    if ((tid & 63) == 0) { ls[wid] = s; lm[wid] = m; }
    __syncthreads();
    if (tid == 0) {
      s = ls[0] + ls[1] + ls[2] + ls[3];
      m = fmaxf(fmaxf(lm[0], lm[1]), fmaxf(lm[2], lm[3]));
      atomicAdd(&accF[1], s);
      atomicMax(&accU[2], fmap(m));
    }
  } else {
    int t = ((bid - 64) << 8) + tid;
    float c = 0.f;
    if (t < NT) {
      int i, j, v0, v1, v2;
      if (t < ED) { i = t / 127; j = t - i * 127; v0 = (i << 7) + j; v1 = v0 + 128; v2 = v0 + 129; } // L
      else { int u = t - ED; i = u / 127; j = u - i * 127; v0 = (i << 7) + j; v1 = v0 + 1; v2 = v0 + 129; } // U
      u32 r0 = r32[v0], r1 = r32[v1], r2 = r32[v2];
      int crit = v0; u32 rm = r0;
      if (r1 < rm) { rm = r1; crit = v1; }
      if (r2 < rm) { rm = r2; crit = v2; }
      float fv = -beta[crit];
      fval[t] = fv;
      ctv[t] = (u16)crit;
      c = fv;
      if (t == 0) fval[OUTERF] = __builtin_inff();
    }
    for (int off = 32; off >= 1; off >>= 1) c += __shfl_down(c, off);
    int wid = tid >> 6;
    if ((tid & 63) == 0) ls[wid] = c;
    __syncthreads();
    if (tid == 0) atomicAdd(&accF[3], ls[0] + ls[1] + ls[2] + ls[3]);
  }
}

// ---------------- K3a: per-vertex crit-face counts into rank buckets ----------------
__global__ void k_cntface(const u16* __restrict__ ctv, const u32* __restrict__ r32, u32* cntR) {
  int v = blockIdx.x * 256 + threadIdx.x;
  int i = v >> 7, j = v & 127;
  int cnt = 0;
  if (i < 127 && j < 127) cnt += (ctv[i * 127 + j] == v);
  if (i >= 1 && j < 127)  cnt += (ctv[(i - 1) * 127 + j] == v);
  if (i >= 1 && j >= 1)   cnt += (ctv[(i - 1) * 127 + (j - 1)] == v);
  if (i < 127 && j < 127) cnt += (ctv[ED + i * 127 + j] == v);
  if (i < 127 && j >= 1)  cnt += (ctv[ED + i * 127 + (j - 1)] == v);
  if (i >= 1 && j >= 1)   cnt += (ctv[ED + (i - 1) * 127 + (j - 1)] == v);
  cntR[r32[v]] = (u32)cnt;
}

// ---------------- K3b: exclusive scan over NV rank buckets (+1: outer face = rank 0) ----------------
__global__ __launch_bounds__(1024) void k_scanR(u32* cntR) {
  __shared__ u32 wsum[16];
  int tid = threadIdx.x;
  u32 loc[16]; u32 s = 0;
#pragma unroll
  for (int k = 0; k < 16; ++k) { u32 c = cntR[(tid << 4) + k]; loc[k] = s; s += c; }
  int lane = tid & 63, wid = tid >> 6;
  u32 incl = s;
  for (int off = 1; off < 64; off <<= 1) {
    u32 o = __shfl_up(incl, off);
    if (lane >= off) incl += o;
  }
  if (lane == 63) wsum[wid] = incl;
  __syncthreads();
  u32 wbase = 0;
  for (int w = 0; w < wid; ++w) wbase += wsum[w];
  u32 base = wbase + incl - s + 1;
#pragma unroll
  for (int k = 0; k < 16; ++k) cntR[(tid << 4) + k] = base + loc[k];
}

// ---------------- K3c: face ranks + rank->value table ----------------
__global__ void k_facerank(const u16* __restrict__ ctv, const u32* __restrict__ r32,
                           const u32* __restrict__ startsR, const float* __restrict__ fval,
                           u32* frk, float* frv) {
  int g = blockIdx.x * 256 + threadIdx.x;
  if (g == 0) { frk[OUTERF] = 0u; frv[0] = __builtin_inff(); }
  if (g >= NT) return;
  int v = ctv[g];
  int i = v >> 7, j = v & 127;
  int local = 0, f;
  if (i < 127 && j < 127) { f = i * 127 + j;             local += (f < g && ctv[f] == v); }
  if (i >= 1 && j < 127)  { f = (i - 1) * 127 + j;       local += (f < g && ctv[f] == v); }
  if (i >= 1 && j >= 1)   { f = (i - 1) * 127 + (j - 1); local += (f < g && ctv[f] == v); }
  if (i < 127 && j < 127) { f = ED + i * 127 + j;        local += (f < g && ctv[f] == v); }
  if (i < 127 && j >= 1)  { f = ED + i * 127 + (j - 1);  local += (f < g && ctv[f] == v); }
  if (i >= 1 && j >= 1)   { f = ED + (i - 1) * 127 + (j - 1); local += (f < g && ctv[f] == v); }
  u32 rk = startsR[r32[v]] + (u32)local;
  frk[g] = rk;
  frv[rk] = fval[g];
}

// ---------------- K4: edge values + records + total sum + ROUND-0 CLAIMS ----------------
__global__ void k_edges(const float* __restrict__ beta, const u32* __restrict__ r32,
                        const u32* __restrict__ frk,
                        float* dvals, uint2* wl0, float* accF, u32* mtabG) {
  int e = blockIdx.x * 256 + threadIdx.x;
  float dv = 0.f;
  if (e < NE) {
    int eu, ev; decode_pe((u32)e, eu, ev);
    int fa, fb; decode_df((u32)e, fa, fb);
    u32 ru = r32[eu], rv = r32[ev];
    u32 rr = min(ru, rv);
    int cv = (ru <= rv) ? eu : ev;
    dv = -beta[cv];
    dvals[e] = dv;
    u32 ra = frk[fa], rb = frk[fb];
    u32 key = (rr << 17) | (u32)e;
    wl0[e] = make_uint2(ra | (rb << 16), key);
    atomicMin(&mtabG[ra], key);                  // claim BOTH roots (round 0)
    atomicMin(&mtabG[rb], key);
  }
  float ds = dv;
  for (int off = 32; off >= 1; off >>= 1) ds += __shfl_down(ds, off);
  if ((threadIdx.x & 63) == 0) atomicAdd(&accF[0], ds);
}

// ---------------- K4b: round-0 win-younger commits (full GPU) ----------------
__global__ void k_win0(const uint2* __restrict__ wl0, const float* __restrict__ dvals,
                       const float* __restrict__ frv, const u32* __restrict__ mtabG,
                       u16* parG, uint2* owl, float* accF, u32* accU) {
  __shared__ float ls[4], lm[4];
  int tid = threadIdx.x, lane = tid & 63;
  int e = blockIdx.x * 256 + tid;
  float wDl = 0.f, lmx = 0.f;
  bool surv = false;
  uint2 rec = make_uint2(0u, 0u);
  if (e < NE) {
    rec = wl0[e];
    u32 a = rec.x & 0xFFFFu, b = rec.x >> 16;
    u32 y = max(a, b), o = min(a, b);
    if (mtabG[y] == rec.y) {
      parG[y] = (u16)o;                          // exact sequential merge
      float dv = dvals[rec.y & 0x1FFFFu];
      wDl = dv;
      lmx = frv[y] - dv;
    } else {
      surv = true;
    }
  }
  unsigned long long mk = __ballot(surv);
  int base = 0;
  if (lane == 0) {
    int c = __popcll(mk);
    if (c) base = (int)atomicAdd(&accU[6], (u32)c);
  }
  base = __shfl(base, 0);
  if (surv) owl[base + __popcll(mk & ((1ull << lane) - 1ull))] = rec;
  for (int off = 32; off >= 1; off >>= 1) {
    wDl += __shfl_down(wDl, off);
    lmx = fmaxf(lmx, __shfl_down(lmx, off));
  }
  if (lane == 0) { ls[tid >> 6] = wDl; lm[tid >> 6] = lmx; }
  __syncthreads();
  if (tid == 0) {
    float s = ls[0] + ls[1] + ls[2] + ls[3];
    float m = fmaxf(fmaxf(lm[0], lm[1]), fmaxf(lm[2], lm[3]));
    atomicAdd(&accF[4], s);
    atomicMax(&accU[5], fmap(m));
  }
}

// ---------------- K4c: generic round-N claims (full GPU) ----------------
// Finds on parG: no hooks during this kernel; path-halving writes replace an
// ancestor pointer with a HIGHER ancestor, so stale reads still yield ancestors
// => correct roots. Claims into a full-size fresh table (no hash collisions).
__global__ void k_claimN(const uint2* __restrict__ wl, u16* parG, u32* rts,
                         u32* mtab, const u32* __restrict__ accU, int ci) {
  int n1 = (int)accU[ci];
  int i = blockIdx.x * 256 + threadIdx.x;
  if (i >= n1) return;
  uint2 rec = wl[i];
  int ra = findh((volatile u16*)parG, (int)(rec.x & 0xFFFFu));
  int rb = findh((volatile u16*)parG, (int)(rec.x >> 16));
  if (ra == rb) {
    rts[i] = 0xFFFFFFFFu;                        // cycle edge: drop
  } else {
    rts[i] = (u32)ra | ((u32)rb << 16);
    atomicMin(&mtab[ra], rec.y);
    atomicMin(&mtab[rb], rec.y);
  }
}

// ---------------- K4d: generic round-N win-younger commits (full GPU) ----------------
__global__ void k_winN(const uint2* __restrict__ wl, const u32* __restrict__ rts,
                       const float* __restrict__ dvals, const float* __restrict__ frv,
                       const u32* __restrict__ mtab, u16* parG, uint2* owl,
                       float* accF, u32* accU, int ci, int co) {
  __shared__ float ls[4], lm[4];
  int tid = threadIdx.x, lane = tid & 63;
  int n1 = (int)accU[ci];
  int i = blockIdx.x * 256 + tid;
  bool active = i < n1;
  float wDl = 0.f, lmx = 0.f;
  bool surv = false;
  u32 pr = 0xFFFFFFFFu, key = 0;
  if (active) {
    key = wl[i].y;
    pr = rts[i];
  }
  if (active && pr != 0xFFFFFFFFu) {
    u32 a = pr & 0xFFFFu, b = pr >> 16;
    u32 y = max(a, b), o = min(a, b);
    if (mtab[y] == key) {
      parG[y] = (u16)o;                          // winner owns y exclusively
      float dv = dvals[key & 0x1FFFFu];
      wDl = dv;
      lmx = frv[y] - dv;
    } else {
      surv = true;
    }
  }
  unsigned long long mk = __ballot(surv);
  int base = 0;
  if (lane == 0) {
    int c = __popcll(mk);
    if (c) base = (int)atomicAdd(&accU[co], (u32)c);
  }
  base = __shfl(base, 0);
  if (surv) owl[base + __popcll(mk & ((1ull << lane) - 1ull))] = make_uint2(pr, key);
  for (int off = 32; off >= 1; off >>= 1) {
    wDl += __shfl_down(wDl, off);
    lmx = fmaxf(lmx, __shfl_down(lmx, off));
  }
  if (lane == 0) { ls[tid >> 6] = wDl; lm[tid >> 6] = lmx; }
  __syncthreads();
  if (tid == 0) {
    float s = ls[0] + ls[1] + ls[2] + ls[3];
    float m = fmaxf(fmaxf(lm[0], lm[1]), fmaxf(lm[2], lm[3]));
    atomicAdd(&accF[4], s);
    atomicMax(&accU[5], fmap(m));
  }
}

// ---------------- K5: unified dual Kruskal from round 4 ----------------
// CLAIM-BOTH / WIN-YOUNGER (proven round 10). par seeded from parG (rounds 0-3
// committed at full GPU). Main loop (usually skipped); LDS tail with compaction
// + A/B claim tables; single-wave finisher with REGISTER-RESIDENT records and
// per-cycle ballot compaction (scan cost ~ live count).
__global__ __launch_bounds__(1024) void k_dual(
    uint2* __restrict__ wlA, uint2* __restrict__ wlB, u32* __restrict__ rts,
    const u32* __restrict__ parG32, const float* __restrict__ dvals,
    const float* __restrict__ frv,
    const float* __restrict__ accF, const u32* __restrict__ accU, float* out) {
  __shared__ u16 par[ND + 1];      // 64520 B
  __shared__ u32 pool[24576];      // 98304 B
  __shared__ int nCur, nNxt;
  __shared__ int nTail[2];
  __shared__ float redS[16], redM[16];
  int tid = threadIdx.x, lane = tid & 63;
  {
    u32* p32 = (u32*)par;
    for (int v = tid; v < (ND + 1) / 2; v += 1024) p32[v] = parG32[v];
  }
  for (int h = tid; h < 16384; h += 1024) pool[h] = 0xFFFFFFFFu;
  if (tid == 0) { nNxt = 0; nTail[0] = 0; nTail[1] = 0; nCur = (int)accU[9]; }
  float wD = 0.f, lmax = 0.f;
  __syncthreads();
  uint2* cur = wlA;
  uint2* nxt = wlB;
  int n = nCur;
  for (int round = 0; round < 50000 && n > TAILN; ++round) {
    for (int i0 = 0; i0 < n; i0 += 1024) {
      int i = i0 + tid;
      if (i < n) {
        uint2 rec = cur[i];
        int ra = findh((volatile u16*)par, (int)(rec.x & 0xFFFFu));
        int rb = findh((volatile u16*)par, (int)(rec.x >> 16));
        if (ra == rb) {
          rts[i] = 0xFFFFFFFFu;
        } else {
          rts[i] = (u32)ra | ((u32)rb << 16);
          atomicMin(&pool[(u32)ra & 16383u], rec.y);
          atomicMin(&pool[(u32)rb & 16383u], rec.y);
        }
      }
    }
    __syncthreads();
    for (int i0 = 0; i0 < n; i0 += 1024) {
      int i = i0 + tid;
      bool active = i < n;
      u32 pr = 0xFFFFFFFFu, key = 0;
      if (active) {
        key = cur[i].y;
        pr = rts[i];
      }
      bool pend = active && (pr != 0xFFFFFFFFu);
      u32 y = 0, o = 0;
      bool win = false;
      if (pend) {
        u32 a = pr & 0xFFFFu, b = pr >> 16;
        y = max(a, b); o = min(a, b);
        win = (pool[y & 16383u] == key);
      }
      if (win) {
        par[y] = (u16)o;
        float dv = dvals[key & 0x1FFFFu];
        wD += dv;
        lmax = fmaxf(lmax, frv[y] - dv);
      }
      bool req = pend && !win;
      unsigned long long mk = __ballot(req);
      int base = 0;
      if (lane == 0) {
        int c = __popcll(mk);
        if (c) base = atomicAdd(&nNxt, c);
      }
      base = __shfl(base, 0);
      if (req) {
        int pos = base + __popcll(mk & ((1ull << lane) - 1ull));
        nxt[pos] = make_uint2(pr, key);
      }
    }
    __syncthreads();
    if (n <= 6144) {
      for (int i0 = 0; i0 < n; i0 += 1024) {
        int i = i0 + tid;
        if (i < n) {
          u32 pr = rts[i];
          if (pr != 0xFFFFFFFFu) {
            pool[(pr & 0xFFFFu) & 16383u] = 0xFFFFFFFFu;
            pool[(pr >> 16) & 16383u] = 0xFFFFFFFFu;
          }
        }
      }
    } else {
      for (int h = tid; h < 16384; h += 1024) pool[h] = 0xFFFFFFFFu;
    }
    for (int v = tid; v < ND; v += 1024) {
      int p = par[v]; int pp = par[p];
      if (p != pp) par[v] = (u16)pp;
    }
    if (tid == 0) { nCur = nNxt; nNxt = 0; }
    __syncthreads();
    n = nCur;
    uint2* s = cur; cur = nxt; nxt = s;
  }
  if (n > 0) {
    uint2* wlL = (uint2*)(pool + 8192);
    for (int i = tid; i < n; i += 1024) wlL[i] = cur[i];
    __syncthreads();
    int nL = n;
    int cb = 0;
    u32 oldp[8];
#pragma unroll
    for (int k = 0; k < 8; ++k) oldp[k] = 0xFFFFFFFFu;
    for (int sr = 0; sr < 100000; ++sr) {
      if (nL <= FINT) break;
      u32* mtC = pool + (cb << 12);
      u32* mtO = pool + ((cb ^ 1) << 12);
      u32 prc[8], keyr[8];
#pragma unroll
      for (int k = 0; k < 8; ++k) {
        if (oldp[k] != 0xFFFFFFFFu) {
          mtO[(oldp[k] & 0xFFFFu) & 4095u] = 0xFFFFFFFFu;
          mtO[(oldp[k] >> 16) & 4095u] = 0xFFFFFFFFu;
        }
        prc[k] = 0xFFFFFFFFu; keyr[k] = 0u;
        int i = tid + (k << 10);
        if (i < nL) {
          uint2 rec = wlL[i];
          int ra = findh((volatile u16*)par, (int)(rec.x & 0xFFFFu));
          int rb = findh((volatile u16*)par, (int)(rec.x >> 16));
          if (ra != rb) {
            u32 pr = (u32)ra | ((u32)rb << 16);
            prc[k] = pr; keyr[k] = rec.y;
            atomicMin(&mtC[(u32)ra & 4095u], rec.y);
            atomicMin(&mtC[(u32)rb & 4095u], rec.y);
          }
        }
      }
      if (tid == 0) nTail[cb] = 0;
      __syncthreads();
#pragma unroll
      for (int k = 0; k < 8; ++k) {
        bool surv = false;
        if (prc[k] != 0xFFFFFFFFu) {
          u32 a = prc[k] & 0xFFFFu, b = prc[k] >> 16;
          u32 y = max(a, b), o = min(a, b);
          if (mtC[y & 4095u] == keyr[k]) {
            par[y] = (u16)o;
            float dv = dvals[keyr[k] & 0x1FFFFu];
            wD += dv;
            lmax = fmaxf(lmax, frv[y] - dv);
          } else {
            surv = true;
          }
        }
        unsigned long long mk = __ballot(surv);
        int base = 0;
        if (lane == 0) {
          int c = __popcll(mk);
          if (c) base = atomicAdd(&nTail[cb], c);
        }
        base = __shfl(base, 0);
        if (surv) {
          int pos = base + __popcll(mk & ((1ull << lane) - 1ull));
          wlL[pos] = make_uint2(prc[k], keyr[k]);
        }
        oldp[k] = prc[k];
      }
      __syncthreads();
      nL = nTail[cb];
      cb ^= 1;
    }
    for (int h = tid; h < 8192; h += 1024) pool[h] = 0xFFFFFFFFu;
    __syncthreads();
    // ---- single-wave finisher: register-resident records + per-cycle compaction ----
    if (nL > 0 && tid < 64) {
      int m = nL;                                  // <= FINT = 1024 = 16 slots
      int guard = 0;
      while (m > 0 && guard++ < 100000) {
        u32 rx[16], ry[16], prc[16];
        // load all live records into registers (compile-time indices)
#pragma unroll
        for (int k = 0; k < 16; ++k) {
          int i = (k << 6) + lane;
          rx[k] = 0xFFFFFFFFu; ry[k] = 0u;
          if (i < m) { uint2 rec = wlL[i]; rx[k] = rec.x; ry[k] = rec.y; }
        }
        asm volatile("s_waitcnt lgkmcnt(0)" ::: "memory");
        // P1: find + claim (all claims before any win-check)
#pragma unroll
        for (int k = 0; k < 16; ++k) {
          prc[k] = 0xFFFFFFFFu;
          if (rx[k] != 0xFFFFFFFFu) {
            int ra = findh((volatile u16*)par, (int)(rx[k] & 0xFFFFu));
            int rb = findh((volatile u16*)par, (int)(rx[k] >> 16));
            if (ra == rb) {
              rx[k] = 0xFFFFFFFFu;                 // cycle edge: dead
            } else {
              prc[k] = (u32)ra | ((u32)rb << 16);
              atomicMin(&pool[(u32)ra & 4095u], ry[k]);
              atomicMin(&pool[(u32)rb & 4095u], ry[k]);
            }
          }
        }
        asm volatile("s_waitcnt lgkmcnt(0)" ::: "memory");
        // P2: win-younger commits
#pragma unroll
        for (int k = 0; k < 16; ++k) {
          if (prc[k] != 0xFFFFFFFFu) {
            u32 a = prc[k] & 0xFFFFu, b = prc[k] >> 16;
            u32 y = max(a, b), o = min(a, b);
            if (pool[y & 4095u] == ry[k]) {
              par[y] = (u16)o;
              float dv = dvals[ry[k] & 0x1FFFFu];
              wD += dv;
              lmax = fmaxf(lmax, frv[y] - dv);
              rx[k] = 0xFFFFFFFFu;                 // committed: dead
            }
          }
        }
        asm volatile("s_waitcnt lgkmcnt(0)" ::: "memory");
        // P3: reset claimed slots
#pragma unroll
        for (int k = 0; k < 16; ++k) {
          if (prc[k] != 0xFFFFFFFFu) {
            pool[(prc[k] & 0xFFFFu) & 4095u] = 0xFFFFFFFFu;
            pool[(prc[k] >> 16) & 4095u] = 0xFFFFFFFFu;
          }
        }
        // P4: ballot-compact survivors (records already in regs; writes safe)
        int mnew = 0;
#pragma unroll
        for (int k = 0; k < 16; ++k) {
          bool lv = (rx[k] != 0xFFFFFFFFu);
          unsigned long long mk = __ballot(lv);
          int pos = mnew + (int)__popcll(mk & ((1ull << lane) - 1ull));
          if (lv) wlL[pos] = make_uint2(prc[k], ry[k]);   // frozen-roots form
          mnew += (int)__popcll(mk);
        }
        asm volatile("s_waitcnt lgkmcnt(0)" ::: "memory");
        m = mnew;
      }
    }
  }
  __syncthreads();
  for (int off = 32; off >= 1; off >>= 1) {
    wD += __shfl_down(wD, off);
    lmax = fmaxf(lmax, __shfl_down(lmax, off));
  }
  if (lane == 0) { redS[tid >> 6] = wD; redM[tid >> 6] = lmax; }
  __syncthreads();
  if (tid == 0) {
    float s = 0.f, m = 0.f;
    for (int w = 0; w < 16; ++w) { s += redS[w]; m = fmaxf(m, redM[w]); }
    s += accF[4];
    m = fmaxf(m, funmap(accU[5]));
    float wmst = accF[0] - s;
    float loss0 = wmst + accF[1] - funmap(accU[2]);
    float sum1 = accF[3] - s;
    out[0] = loss0 + sum1 - m;
  }
}

extern "C" void kernel_launch(void* const* d_in, const int* in_sizes, int n_in,
                              void* d_out, int out_size, void* d_ws, size_t ws_size,
                              hipStream_t stream) {
  const float* beta = (const float*)d_in[0];
  float* out = (float*)d_out;
  char* ws = (char*)d_ws;
  float* accF = (float*)(ws + OFF_ACC);
  u32*   accU = (u32*)(ws + OFF_ACC);
  u32* r32 = (u32*)(ws + OFF_R32);
  float* fval = (float*)(ws + OFF_FVAL);
  u16* ctv = (u16*)(ws + OFF_CTV);
  u32* cntR = (u32*)(ws + OFF_CNTR);
  u32* frk = (u32*)(ws + OFF_FRK);
  float* frv = (float*)(ws + OFF_FRV);
  float* dvals = (float*)(ws + OFF_DVAL);
  uint2* wlA = (uint2*)(ws + OFF_WLA);
  uint2* wlB = (uint2*)(ws + OFF_WLB);
  u32* rts = (u32*)(ws + OFF_RTS);
  u32* mtabG = (u32*)(ws + OFF_MTG);
  u32* mtabG2 = (u32*)(ws + OFF_MTG2);
  u32* mtabG3 = (u32*)(ws + OFF_MTG3);
  u32* mtabG4 = (u32*)(ws + OFF_MTG4);
  u16* parG = (u16*)(ws + OFF_PARG);
  u32* parG32 = (u32*)(ws + OFF_PARG);

  hipLaunchKernelGGL(k_init, dim3(127), dim3(256), 0, stream, accF, r32, mtabG, mtabG2, mtabG3, mtabG4, parG32);
  hipLaunchKernelGGL(k_rankv, dim3(64, 16), dim3(256), 0, stream, beta, r32);
  hipLaunchKernelGGL(k_build, dim3(191), dim3(256), 0, stream, beta, r32, fval, ctv, accF, accU);
  hipLaunchKernelGGL(k_cntface, dim3(64), dim3(256), 0, stream, ctv, r32, cntR);
  hipLaunchKernelGGL(k_scanR, dim3(1), dim3(1024), 0, stream, cntR);
  hipLaunchKernelGGL(k_facerank, dim3(127), dim3(256), 0, stream, ctv, r32, cntR, fval, frk, frv);
  // round 0 (claims fused into k_edges)
  hipLaunchKernelGGL(k_edges, dim3(191), dim3(256), 0, stream, beta, r32, frk, dvals, wlA, accF, mtabG);
  hipLaunchKernelGGL(k_win0, dim3(191), dim3(256), 0, stream, wlA, dvals, frv, mtabG, parG, wlB, accF, accU);
  // round 1: wlB -> wlA  (cnt U6 -> U7), fresh table mtabG2
  hipLaunchKernelGGL(k_claimN, dim3(191), dim3(256), 0, stream, wlB, parG, rts, mtabG2, accU, 6);
  hipLaunchKernelGGL(k_winN, dim3(191), dim3(256), 0, stream, wlB, rts, dvals, frv, mtabG2, parG, wlA, accF, accU, 6, 7);
  // round 2: wlA -> wlB  (cnt U7 -> U8), fresh table mtabG3
  hipLaunchKernelGGL(k_claimN, dim3(191), dim3(256), 0, stream, wlA, parG, rts, mtabG3, accU, 7);
  hipLaunchKernelGGL(k_winN, dim3(191), dim3(256), 0, stream, wlA, rts, dvals, frv, mtabG3, parG, wlB, accF, accU, 7, 8);
  // round 3: wlB -> wlA  (cnt U8 -> U9), fresh table mtabG4
  hipLaunchKernelGGL(k_claimN, dim3(191), dim3(256), 0, stream, wlB, parG, rts, mtabG4, accU, 8);
  hipLaunchKernelGGL(k_winN, dim3(191), dim3(256), 0, stream, wlB, rts, dvals, frv, mtabG4, parG, wlA, accF, accU, 8, 9);
  // remaining rounds + tail + output on one CU
  hipLaunchKernelGGL(k_dual, dim3(1), dim3(1024), 0, stream, wlA, wlB, rts, parG32, dvals, frv, accF, accU, out);
}